// Round 7
// baseline (357.051 us; speedup 1.0000x reference)
//
#include <hip/hip_runtime.h>
#include <hip/hip_bf16.h>

typedef _Float16 f16;
typedef _Float16 f16x8 __attribute__((ext_vector_type(8)));
typedef _Float16 f16x4 __attribute__((ext_vector_type(4)));
typedef float f32x4 __attribute__((ext_vector_type(4)));

#define MFMA16(a, b, c) __builtin_amdgcn_mfma_f32_16x16x32_f16((a), (b), (c), 0, 0, 0)
#define MFMA16K16(a, b, c) __builtin_amdgcn_mfma_f32_16x16x16f16((a), (b), (c), 0, 0, 0)

__device__ __forceinline__ void load16(const void* g, void* l) {
    __builtin_amdgcn_global_load_lds((const __attribute__((address_space(1))) void*)g,
                                     (__attribute__((address_space(3))) void*)l, 16, 0, 0);
}

// ---------------------------------------------------------------- prep (fused)
// blocks 0..8191      : x0,x1 fp32 -> xh f16
// blocks 8192..8703   : wcat_t[n][k] = [Wqk^T; Wv^T]
// blocks 8704..9215   : w1t[n][k<256] = W1_top^T
// blocks 9216..9727   : w2t[n][k] = W2[k][n]
// blocks 9728..10239  : w1t[n][256+u] = sum_j Wout[u][j] * W1[256+j][n]  (Wout fold)
// blocks 10240..10751 : bias_eff[n] = b1[n] + sum_j bout[j]*W1[256+j][n]
__global__ __launch_bounds__(256) void k_prep(const float* __restrict__ x0,
                                              const float* __restrict__ x1,
                                              const float* __restrict__ Wqk,
                                              const float* __restrict__ Wv,
                                              const float* __restrict__ W1,
                                              const float* __restrict__ W2,
                                              const float* __restrict__ Wout,
                                              const float* __restrict__ b1,
                                              const float* __restrict__ bout,
                                              f16* __restrict__ xh, f16* __restrict__ wcat_t,
                                              f16* __restrict__ w1t, f16* __restrict__ w2t,
                                              float* __restrict__ bias_eff) {
    __shared__ float lbuf[256];
    __shared__ float red[4];
    const int blk = blockIdx.x, tid = threadIdx.x;
    if (blk < 8192) {
        size_t i = ((size_t)blk * 256 + tid) * 4;
        const float* src = (i < 4194304) ? (x0 + i) : (x1 + (i - 4194304));
        float4 v = *(const float4*)src;
        f16x4 o = {(f16)v.x, (f16)v.y, (f16)v.z, (f16)v.w};
        *(f16x4*)(xh + i) = o;
    } else if (blk < 8704) {
        int n = blk - 8192;
        const float* W = (n < 256) ? Wqk : Wv;
        wcat_t[n * 256 + tid] = (f16)W[tid * 256 + (n & 255)];
    } else if (blk < 9216) {
        int n = blk - 8704;
        w1t[n * 512 + tid] = (f16)W1[tid * 512 + n];
    } else if (blk < 9728) {
        int j = blk - 9216;
        int n = j >> 1, k = (j & 1) * 256 + tid;
        w2t[n * 512 + k] = (f16)W2[k * 256 + n];
    } else if (blk < 10240) {
        int n = blk - 9728;  // column of W1_bot / output row of w1t right half
        lbuf[tid] = W1[(size_t)(256 + tid) * 512 + n];
        __syncthreads();
        const float* wr = Wout + (size_t)tid * 256;  // row u = tid
        float s = 0.f;
#pragma unroll 8
        for (int t = 0; t < 256; t++) s += lbuf[t] * wr[t];
        w1t[n * 512 + 256 + tid] = (f16)s;
    } else {
        int n = blk - 10240;
        float s = bout[tid] * W1[(size_t)(256 + tid) * 512 + n];
#pragma unroll
        for (int off = 1; off < 64; off <<= 1) s += __shfl_xor(s, off);
        int wave = tid >> 6, lane = tid & 63;
        if (lane == 0) red[wave] = s;
        __syncthreads();
        if (tid == 0) bias_eff[n] = b1[n] + red[0] + red[1] + red[2] + red[3];
    }
}

// ---------------------------------------------------------------- generic GEMM v2
// C[M][N] = A[M][K] (f16) @ Bt[N][K]^T (f16), fp32 accum.
// Grid: x = bm (fast), y = bn. gridDim.x = 256 == 0 mod 8, so a given A row-tile
// maps to the same XCD for every bn pass -> A re-reads served from that XCD's L2.
// mode 0: proj  -> n<256: (v+bqk)*scale to qk (2,B,H,L,D); n>=256: v+bv to vt (2,B,H,D,L)
// mode 2: f16 out [M][N] = v + bias1[n]
// mode 3: f32 out [M][256] = v + bias1[n] + (float)resh[m][n] (f16 residual)
__global__ __launch_bounds__(256) void k_gemm(const f16* __restrict__ A1,
                                              const f16* __restrict__ A2, int ksplit,
                                              int strideA, const f16* __restrict__ Bt, int K,
                                              int N, const float* __restrict__ bias1,
                                              const float* __restrict__ bias2, int mode,
                                              void* __restrict__ out1, void* __restrict__ out2,
                                              const f16* __restrict__ resh) {
    const int bm0 = blockIdx.x * 128;
    const int bn0 = blockIdx.y * 128;
    __shared__ f16 As[2][4096];  // [128 rows][32 k] in 16B chunks, chunk ^ (row&3)
    __shared__ f16 Bs[2][4096];
    const int tid = threadIdx.x;
    const int lane = tid & 63, wave = tid >> 6;
    const int quad = lane >> 4, l16 = lane & 15;
    const int wm0 = (wave & 1) * 64, wn0 = (wave >> 1) * 64;
    const int axor = l16 & 3;

    f32x4 acc[4][4];
#pragma unroll
    for (int tm = 0; tm < 4; tm++)
#pragma unroll
        for (int tn = 0; tn < 4; tn++) acc[tm][tn] = (f32x4){0.f, 0.f, 0.f, 0.f};

    auto stage = [&](int buf, int kt) {
        const int k0 = kt * 32;
        const f16* Ab = (k0 < ksplit) ? A1 : A2;
        const int koff = (k0 < ksplit) ? k0 : k0 - ksplit;
#pragma unroll
        for (int rd = 0; rd < 2; rd++) {
            const int cbase = rd * 256 + wave * 64;
            const int c = cbase + lane;
            const int row = c >> 2, col = (c & 3) ^ (row & 3);
            load16(Ab + (size_t)(bm0 + row) * strideA + koff + col * 8, &As[buf][cbase * 8]);
        }
#pragma unroll
        for (int rd = 0; rd < 2; rd++) {
            const int cbase = rd * 256 + wave * 64;
            const int c = cbase + lane;
            const int row = c >> 2, col = (c & 3) ^ (row & 3);
            load16(Bt + (size_t)(bn0 + row) * K + k0 + col * 8, &Bs[buf][cbase * 8]);
        }
    };

    const int NT = K >> 5;
    stage(0, 0);
    __syncthreads();
    for (int kt = 0; kt < NT; kt++) {
        const int cur = kt & 1;
        if (kt + 1 < NT) stage(cur ^ 1, kt + 1);
        f16x8 af[4], bf[4];
#pragma unroll
        for (int t = 0; t < 4; t++)
            af[t] = *(const f16x8*)&As[cur][(wm0 + t * 16 + l16) * 32 + (quad ^ axor) * 8];
#pragma unroll
        for (int t = 0; t < 4; t++)
            bf[t] = *(const f16x8*)&Bs[cur][(wn0 + t * 16 + l16) * 32 + (quad ^ axor) * 8];
#pragma unroll
        for (int tm = 0; tm < 4; tm++)
#pragma unroll
            for (int tn = 0; tn < 4; tn++) acc[tm][tn] = MFMA16(bf[tn], af[tm], acc[tm][tn]);
        __syncthreads();
    }

#pragma unroll
    for (int tm = 0; tm < 4; tm++) {
        const int m = bm0 + wm0 + tm * 16 + l16;
#pragma unroll
        for (int tn = 0; tn < 4; tn++) {
            const int n = bn0 + wn0 + tn * 16 + quad * 4;
            f32x4 v = acc[tm][tn];
            if (mode == 0) {
                const int s = m >> 14, r14 = m & 16383, b = r14 >> 11, l = r14 & 2047;
                if (n < 256) {
                    float4 bi = *(const float4*)(bias1 + n);
                    const int h = n >> 6, d = n & 63;
                    const size_t hh = (size_t)((s * 8 + b) * 4 + h);
                    // scale = D^-0.25 * sqrt(log2(e)) so flash softmax uses exp2
                    f16x4 o = {(f16)((v[0] + bi.x) * 0.42466090f),
                               (f16)((v[1] + bi.y) * 0.42466090f),
                               (f16)((v[2] + bi.z) * 0.42466090f),
                               (f16)((v[3] + bi.w) * 0.42466090f)};
                    *(f16x4*)((f16*)out1 + (hh * 2048 + l) * 64 + d) = o;
                } else {
                    const int n2 = n - 256;
                    float4 bi = *(const float4*)(bias2 + n2);
                    const int h = n2 >> 6, d = n2 & 63;
                    const size_t hh = (size_t)((s * 8 + b) * 4 + h);
                    f16* o2 = (f16*)out2 + (hh * 64 + d) * 2048 + l;
                    o2[0] = (f16)(v[0] + bi.x);
                    o2[2048] = (f16)(v[1] + bi.y);
                    o2[4096] = (f16)(v[2] + bi.z);
                    o2[6144] = (f16)(v[3] + bi.w);
                }
            } else if (mode == 2) {
                float4 bi = *(const float4*)(bias1 + n);
                f16x4 o = {(f16)(v[0] + bi.x), (f16)(v[1] + bi.y), (f16)(v[2] + bi.z),
                           (f16)(v[3] + bi.w)};
                *(f16x4*)((f16*)out1 + (size_t)m * N + n) = o;
            } else {  // mode 3
                float4 bi = *(const float4*)(bias1 + n);
                f16x4 rr = *(const f16x4*)(resh + (size_t)m * 256 + n);
                float4 o = {v[0] + bi.x + (float)rr[0], v[1] + bi.y + (float)rr[1],
                            v[2] + bi.z + (float)rr[2], v[3] + bi.w + (float)rr[3]};
                *(float4*)((float*)out1 + (size_t)m * 256 + n) = o;
            }
        }
    }
}

// ---------------------------------------------------------------- flash attention (S^T form)
// S^T = K Q^T; P^T feeds O^T = V^T P^T directly (B-frag of mfma_16x16x16).
// Fixed-shift softmax P = exp2(s-8) (shift-invariant; log2e folded upstream).
// 128-q tile (tq=2): ka/va LDS fragments are shared across both tq sub-tiles,
// halving LDS reads per MFMA vs a 64-q tile (R6 regression). Grid x=bh (fast):
// all 16 q-tiles of one K/V panel land on one XCD -> panel served from L2.
__global__ __launch_bounds__(256, 4) void k_flash(const f16* __restrict__ qkbuf,
                                                  const f16* __restrict__ vtbuf,
                                                  f16* __restrict__ mbuf) {
    const int z = blockIdx.z;
    const int bh = blockIdx.x;  // b*4+h (fast dim -> XCD-panel affinity)
    const int qt = blockIdx.y;  // 0..15
    const size_t HSZ = 2048 * 64;
    const size_t SSZ = 32 * HSZ;
    const f16* Q = qkbuf + (z ? SSZ : 0) + bh * HSZ;
    const f16* Kp = qkbuf + (z ? 0 : SSZ) + bh * HSZ;
    const f16* Vt = vtbuf + (z ? 0 : SSZ) + bh * HSZ;
    f16* Mo = mbuf + (size_t)z * (16384 * 256);

    __shared__ f16 Ks[2][4096];  // 64 rows x 64 cols, xor-swizzled 16B chunks
    __shared__ f16 Vs[2][4096];  // 64 d-rows x 64 kv-cols, same swizzle

    const int tid = threadIdx.x, lane = tid & 63, wave = tid >> 6;
    const int quad = lane >> 4, l16 = lane & 15;
    const int srow = lane >> 3;
    const int slc = (lane & 7) ^ (srow & 7);

    const int q0 = qt * 128 + wave * 32;
    f16x8 qf[2][2];
#pragma unroll
    for (int tq = 0; tq < 2; tq++)
#pragma unroll
        for (int kk = 0; kk < 2; kk++)
            qf[tq][kk] =
                *(const f16x8*)(Q + (size_t)(q0 + tq * 16 + l16) * 64 + kk * 32 + quad * 8);

    auto stage = [&](int buf, int kv0) {
#pragma unroll
        for (int i = 0; i < 2; i++) {
            const int widx = wave * 2 + i;
            const int row = widx * 8 + srow;
            load16(Kp + (size_t)(kv0 + row) * 64 + slc * 8, &Ks[buf][widx * 512]);
            load16(Vt + (size_t)row * 2048 + kv0 + slc * 8, &Vs[buf][widx * 512]);
        }
    };

    f32x4 oacc[4][2];
#pragma unroll
    for (int td = 0; td < 4; td++)
#pragma unroll
        for (int tq = 0; tq < 2; tq++) oacc[td][tq] = (f32x4){0.f, 0.f, 0.f, 0.f};
    float lrow[2] = {0.f, 0.f};

    stage(0, 0);
    __syncthreads();

    for (int t = 0; t < 32; t++) {
        const int cur = t & 1;
        if (t < 31) stage(cur ^ 1, (t + 1) * 64);
        const f16* Kc = Ks[cur];
        const f16* Vc = Vs[cur];

        f32x4 sacc[4][2];
#pragma unroll
        for (int tkv = 0; tkv < 4; tkv++)
#pragma unroll
            for (int tq = 0; tq < 2; tq++) sacc[tkv][tq] = (f32x4){0.f, 0.f, 0.f, 0.f};
#pragma unroll
        for (int kk = 0; kk < 2; kk++) {
#pragma unroll
            for (int tkv = 0; tkv < 4; tkv++) {
                const int r = tkv * 16 + l16;
                f16x8 ka = *(const f16x8*)(Kc + r * 64 + (((kk * 4 + quad) ^ (r & 7)) * 8));
#pragma unroll
                for (int tq = 0; tq < 2; tq++)
                    sacc[tkv][tq] = MFMA16(ka, qf[tq][kk], sacc[tkv][tq]);
            }
        }

        // fixed-shift softmax: P = exp2(s - 8), per-lane l partials only
        f16x4 pk[4][2];
#pragma unroll
        for (int tq = 0; tq < 2; tq++) {
            float rs = 0.f;
#pragma unroll
            for (int tkv = 0; tkv < 4; tkv++) {
                float p0 = __builtin_amdgcn_exp2f(sacc[tkv][tq][0] - 8.0f);
                float p1 = __builtin_amdgcn_exp2f(sacc[tkv][tq][1] - 8.0f);
                float p2 = __builtin_amdgcn_exp2f(sacc[tkv][tq][2] - 8.0f);
                float p3 = __builtin_amdgcn_exp2f(sacc[tkv][tq][3] - 8.0f);
                pk[tkv][tq] = (f16x4){(f16)p0, (f16)p1, (f16)p2, (f16)p3};
                rs += (p0 + p1) + (p2 + p3);
            }
            lrow[tq] += rs;
        }

#pragma unroll
        for (int tkv = 0; tkv < 4; tkv++) {
#pragma unroll
            for (int td = 0; td < 4; td++) {
                const int r = td * 16 + l16;
                f16x4 va = *(const f16x4*)(Vc + r * 64 +
                                           (((2 * tkv + (quad >> 1)) ^ (r & 7)) * 8) +
                                           (quad & 1) * 4);
#pragma unroll
                for (int tq = 0; tq < 2; tq++)
                    oacc[td][tq] = MFMA16K16(va, pk[tkv][tq], oacc[td][tq]);
            }
        }
        __syncthreads();
    }

    const int b = bh >> 2, h = bh & 3;
#pragma unroll
    for (int tq = 0; tq < 2; tq++) {
        float ls = lrow[tq];
        ls += __shfl_xor(ls, 16);
        ls += __shfl_xor(ls, 32);
        const float inv = 1.f / ls;
        const int q = q0 + tq * 16 + l16;
        const size_t base = ((size_t)(b * 2048 + q)) * 256 + h * 64;
#pragma unroll
        for (int td = 0; td < 4; td++) {
            f16x4 o = {(f16)(oacc[td][tq][0] * inv), (f16)(oacc[td][tq][1] * inv),
                       (f16)(oacc[td][tq][2] * inv), (f16)(oacc[td][tq][3] * inv)};
            *(f16x4*)(Mo + base + td * 16 + quad * 4) = o;
        }
    }
}

// ---------------------------------------------------------------- LN + GELU (wave per row)
__global__ __launch_bounds__(256) void k_ln_gelu(f16* __restrict__ h,
                                                 const float* __restrict__ g,
                                                 const float* __restrict__ bb) {
    const int tid = threadIdx.x, wave = tid >> 6, lane = tid & 63;
    const size_t row = (size_t)blockIdx.x * 4 + wave;
    f16* hr = h + row * 512 + lane * 8;
    f16x8 v = *(const f16x8*)hr;
    float x[8];
    float s = 0.f, sq = 0.f;
#pragma unroll
    for (int i = 0; i < 8; i++) {
        x[i] = (float)v[i];
        s += x[i];
        sq += x[i] * x[i];
    }
#pragma unroll
    for (int off = 1; off < 64; off <<= 1) {
        s += __shfl_xor(s, off);
        sq += __shfl_xor(sq, off);
    }
    const float mu = s * (1.f / 512.f);
    const float var = sq * (1.f / 512.f) - mu * mu;
    const float rstd = rsqrtf(var + 1e-5f);
    float4 g0 = *(const float4*)(g + lane * 8), g1 = *(const float4*)(g + lane * 8 + 4);
    float4 b0 = *(const float4*)(bb + lane * 8), b1 = *(const float4*)(bb + lane * 8 + 4);
    float gg[8] = {g0.x, g0.y, g0.z, g0.w, g1.x, g1.y, g1.z, g1.w};
    float bv[8] = {b0.x, b0.y, b0.z, b0.w, b1.x, b1.y, b1.z, b1.w};
#pragma unroll
    for (int i = 0; i < 8; i++) {
        float a = (x[i] - mu) * rstd * gg[i] + bv[i];
        a = 0.5f * a * (1.f + erff(a * 0.70710678118f));
        v[i] = (f16)a;
    }
    *(f16x8*)hr = v;
}

// ---------------------------------------------------------------- launch

extern "C" void kernel_launch(void* const* d_in, const int* in_sizes, int n_in, void* d_out,
                              int out_size, void* d_ws, size_t ws_size, hipStream_t stream) {
    const float* x0 = (const float*)d_in[0];
    const float* x1 = (const float*)d_in[1];
    const float* Wqk = (const float*)d_in[2];
    const float* bqk = (const float*)d_in[3];
    const float* Wv = (const float*)d_in[4];
    const float* bv = (const float*)d_in[5];
    const float* Wout = (const float*)d_in[6];
    const float* bout = (const float*)d_in[7];
    const float* W1 = (const float*)d_in[8];
    const float* b1 = (const float*)d_in[9];
    const float* lng = (const float*)d_in[10];
    const float* lnb = (const float*)d_in[11];
    const float* W2 = (const float*)d_in[12];
    const float* b2 = (const float*)d_in[13];
    float* out = (float*)d_out;

    char* ws = (char*)d_ws;
    f16* xh = (f16*)(ws);                 // 0..16M   (2,B,L,C) f16
    f16* qk = (f16*)(ws + 16777216);      // 16..32M  (2,B,H,L,D) f16 (scaled)
    f16* vt = (f16*)(ws + 33554432);      // 32..48M  (2,B,H,D,L) f16
    f16* mbuf = (f16*)(ws + 50331648);    // 48..64M  (2,B,L,C) f16 (flash out)
    f16* hbuf = qk;                       // 16..48M  (2,B,L,2C) f16 (qk+vt dead after flash)
    // persistent weights
    f16* wcat_t = (f16*)(ws + 67108864);  // [512][256]
    f16* w1t = wcat_t + 131072;           // [512][512] effective W1 (Wout folded)
    f16* w2t = w1t + 262144;              // [256][512]
    float* bias_eff = (float*)(w2t + 131072);  // [512] f32

    k_prep<<<10752, 256, 0, stream>>>(x0, x1, Wqk, Wv, W1, W2, Wout, b1, bout, xh, wcat_t, w1t,
                                      w2t, bias_eff);
    // projections: [x0;x1] @ [Wqk|Wv] -> qk (scaled, head layout) + v^T
    k_gemm<<<dim3(256, 4), 256, 0, stream>>>(xh, xh, 1 << 30, 256, wcat_t, 256, 512, bqk, bv, 0,
                                             qk, vt, nullptr);
    // bidirectional flash attention -> mbuf
    k_flash<<<dim3(32, 16, 2), 256, 0, stream>>>(qk, vt, mbuf);
    // FFN1: [x | attn] @ Weff + bias_eff   (Wout folded in)
    k_gemm<<<dim3(256, 4), 256, 0, stream>>>(xh, mbuf, 256, 256, w1t, 512, 512, bias_eff,
                                             nullptr, 2, hbuf, nullptr, nullptr);
    k_ln_gelu<<<8192, 256, 0, stream>>>(hbuf, lng, lnb);
    // FFN2 + residual (f16 xh) -> fp32 out
    k_gemm<<<dim3(256, 2), 256, 0, stream>>>(hbuf, hbuf, 1 << 30, 512, w2t, 512, 256, b2,
                                             nullptr, 3, out, nullptr, xh);
}

// Round 8
// 318.166 us; speedup vs baseline: 1.1222x; 1.1222x over previous
//
#include <hip/hip_runtime.h>
#include <hip/hip_bf16.h>

typedef _Float16 f16;
typedef _Float16 f16x8 __attribute__((ext_vector_type(8)));
typedef _Float16 f16x4 __attribute__((ext_vector_type(4)));
typedef float f32x4 __attribute__((ext_vector_type(4)));

#define MFMA16(a, b, c) __builtin_amdgcn_mfma_f32_16x16x32_f16((a), (b), (c), 0, 0, 0)
#define MFMA16K16(a, b, c) __builtin_amdgcn_mfma_f32_16x16x16f16((a), (b), (c), 0, 0, 0)

__device__ __forceinline__ void load16(const void* g, void* l) {
    __builtin_amdgcn_global_load_lds((const __attribute__((address_space(1))) void*)g,
                                     (__attribute__((address_space(3))) void*)l, 16, 0, 0);
}

// ---------------------------------------------------------------- prep (fused)
// R6 layout (NO Wout-fold here: folding it into prep cost ~35us twice, R5/R7 —
// the 256-iter serial-loop blocks straggle at the tail of the dispatch).
// blocks 0..8191      : x0,x1 fp32 -> xh f16
// blocks 8192..8703   : wcat_t[n][k] = [Wqk^T; Wv^T]
// blocks 8704..9215   : w1t[n][k<256] = W1_top^T
// blocks 9216..9727   : w1bt[n][t] = W1[256+t][n]
// blocks 9728..10239  : w2t[n][k] = W2[k][n]
// blocks 10240..10495 : woutf16 = (f16)Wout
// blocks 10496..11007 : bias_eff[n] = b1[n] + sum_j bout[j]*W1[256+j][n]
__global__ __launch_bounds__(256) void k_prep(const float* __restrict__ x0,
                                              const float* __restrict__ x1,
                                              const float* __restrict__ Wqk,
                                              const float* __restrict__ Wv,
                                              const float* __restrict__ W1,
                                              const float* __restrict__ W2,
                                              const float* __restrict__ Wout,
                                              const float* __restrict__ b1,
                                              const float* __restrict__ bout,
                                              f16* __restrict__ xh, f16* __restrict__ wcat_t,
                                              f16* __restrict__ w1t, f16* __restrict__ w1bt,
                                              f16* __restrict__ w2t, f16* __restrict__ woutf16,
                                              float* __restrict__ bias_eff) {
    __shared__ float red[4];
    const int blk = blockIdx.x, tid = threadIdx.x;
    if (blk < 8192) {
        size_t i = ((size_t)blk * 256 + tid) * 4;
        const float* src = (i < 4194304) ? (x0 + i) : (x1 + (i - 4194304));
        float4 v = *(const float4*)src;
        f16x4 o = {(f16)v.x, (f16)v.y, (f16)v.z, (f16)v.w};
        *(f16x4*)(xh + i) = o;
    } else if (blk < 8704) {
        int n = blk - 8192;
        const float* W = (n < 256) ? Wqk : Wv;
        wcat_t[n * 256 + tid] = (f16)W[tid * 256 + (n & 255)];
    } else if (blk < 9216) {
        int n = blk - 8704;
        w1t[n * 512 + tid] = (f16)W1[tid * 512 + n];
    } else if (blk < 9728) {
        int n = blk - 9216;
        w1bt[n * 256 + tid] = (f16)W1[(256 + tid) * 512 + n];
    } else if (blk < 10240) {
        int j = blk - 9728;
        int n = j >> 1, k = (j & 1) * 256 + tid;
        w2t[n * 512 + k] = (f16)W2[k * 256 + n];
    } else if (blk < 10496) {
        int o = (blk - 10240) * 256 + tid;
        woutf16[o] = (f16)Wout[o];
    } else {
        int n = blk - 10496;
        float s = bout[tid] * W1[(size_t)(256 + tid) * 512 + n];
#pragma unroll
        for (int off = 1; off < 64; off <<= 1) s += __shfl_xor(s, off);
        int wave = tid >> 6, lane = tid & 63;
        if (lane == 0) red[wave] = s;
        __syncthreads();
        if (tid == 0) bias_eff[n] = b1[n] + red[0] + red[1] + red[2] + red[3];
    }
}

// ---------------------------------------------------------------- GEMM, 128m x 256n tile
// C[M][N] = A[M][K] (f16) @ Bt[N][K]^T (f16), fp32 accum. Wide n-tile halves the
// number of bn passes -> halves A re-fetch traffic (FFN1 256->128 MB; FFN2
// single-pass). Grid x = bm (fast): bm%8 pins a row-tile's passes to one XCD.
// mode 0: proj  -> bn0=0: (v+bqk)*scale to qk (2,B,H,L,D); bn0=256: v+bv to vt (2,B,H,D,L)
// mode 2: f16 out [M][N] = v + bias1[n]
// mode 3: f32 out [M][256] = v + bias1[n] + (float)resh[m][n]
// mode 4: f16 out[m][256+n] stride 512, no bias (WoW1b -> w1t right half)
__global__ __launch_bounds__(256, 2) void k_gemm(const f16* __restrict__ A1,
                                                 const f16* __restrict__ A2, int ksplit,
                                                 int strideA, const f16* __restrict__ Bt, int K,
                                                 int N, const float* __restrict__ bias1,
                                                 const float* __restrict__ bias2, int mode,
                                                 void* __restrict__ out1, void* __restrict__ out2,
                                                 const f16* __restrict__ resh) {
    const int bm0 = blockIdx.x * 128;
    const int bn0 = blockIdx.y * 256;
    __shared__ f16 As[2][4096];  // [128 rows][32 k] 16B chunks, chunk ^ (row&3)
    __shared__ f16 Bs[2][8192];  // [256 rows][32 k]
    const int tid = threadIdx.x;
    const int lane = tid & 63, wave = tid >> 6;
    const int quad = lane >> 4, l16 = lane & 15;
    const int wm0 = (wave & 1) * 64, wn0 = (wave >> 1) * 128;
    const int axor = l16 & 3;

    f32x4 acc[4][8];
#pragma unroll
    for (int tm = 0; tm < 4; tm++)
#pragma unroll
        for (int tn = 0; tn < 8; tn++) acc[tm][tn] = (f32x4){0.f, 0.f, 0.f, 0.f};

    auto stage = [&](int buf, int kt) {
        const int k0 = kt * 32;
        const f16* Ab = (k0 < ksplit) ? A1 : A2;
        const int koff = (k0 < ksplit) ? k0 : k0 - ksplit;
#pragma unroll
        for (int rd = 0; rd < 2; rd++) {
            const int cbase = rd * 256 + wave * 64;
            const int c = cbase + lane;
            const int row = c >> 2, col = (c & 3) ^ (row & 3);
            load16(Ab + (size_t)(bm0 + row) * strideA + koff + col * 8, &As[buf][cbase * 8]);
        }
#pragma unroll
        for (int rd = 0; rd < 4; rd++) {
            const int cbase = rd * 256 + wave * 64;
            const int c = cbase + lane;
            const int row = c >> 2, col = (c & 3) ^ (row & 3);
            load16(Bt + (size_t)(bn0 + row) * K + k0 + col * 8, &Bs[buf][cbase * 8]);
        }
    };

    const int NT = K >> 5;
    stage(0, 0);
    __syncthreads();
    for (int kt = 0; kt < NT; kt++) {
        const int cur = kt & 1;
        if (kt + 1 < NT) stage(cur ^ 1, kt + 1);
        f16x8 af[4], bf[8];
#pragma unroll
        for (int t = 0; t < 4; t++)
            af[t] = *(const f16x8*)&As[cur][(wm0 + t * 16 + l16) * 32 + (quad ^ axor) * 8];
#pragma unroll
        for (int t = 0; t < 8; t++)
            bf[t] = *(const f16x8*)&Bs[cur][(wn0 + t * 16 + l16) * 32 + (quad ^ axor) * 8];
#pragma unroll
        for (int tm = 0; tm < 4; tm++)
#pragma unroll
            for (int tn = 0; tn < 8; tn++) acc[tm][tn] = MFMA16(bf[tn], af[tm], acc[tm][tn]);
        __syncthreads();
    }

#pragma unroll
    for (int tm = 0; tm < 4; tm++) {
        const int m = bm0 + wm0 + tm * 16 + l16;
#pragma unroll
        for (int tn = 0; tn < 8; tn++) {
            const int n = bn0 + wn0 + tn * 16 + quad * 4;
            f32x4 v = acc[tm][tn];
            if (mode == 0) {
                const int s = m >> 14, r14 = m & 16383, b = r14 >> 11, l = r14 & 2047;
                if (n < 256) {
                    float4 bi = *(const float4*)(bias1 + n);
                    const int h = n >> 6, d = n & 63;
                    const size_t hh = (size_t)((s * 8 + b) * 4 + h);
                    // scale = D^-0.25 * sqrt(log2(e)) so flash softmax uses exp2
                    f16x4 o = {(f16)((v[0] + bi.x) * 0.42466090f),
                               (f16)((v[1] + bi.y) * 0.42466090f),
                               (f16)((v[2] + bi.z) * 0.42466090f),
                               (f16)((v[3] + bi.w) * 0.42466090f)};
                    *(f16x4*)((f16*)out1 + (hh * 2048 + l) * 64 + d) = o;
                } else {
                    const int n2 = n - 256;
                    float4 bi = *(const float4*)(bias2 + n2);
                    const int h = n2 >> 6, d = n2 & 63;
                    const size_t hh = (size_t)((s * 8 + b) * 4 + h);
                    f16* o2 = (f16*)out2 + (hh * 64 + d) * 2048 + l;
                    o2[0] = (f16)(v[0] + bi.x);
                    o2[2048] = (f16)(v[1] + bi.y);
                    o2[4096] = (f16)(v[2] + bi.z);
                    o2[6144] = (f16)(v[3] + bi.w);
                }
            } else if (mode == 2) {
                float4 bi = *(const float4*)(bias1 + n);
                f16x4 o = {(f16)(v[0] + bi.x), (f16)(v[1] + bi.y), (f16)(v[2] + bi.z),
                           (f16)(v[3] + bi.w)};
                *(f16x4*)((f16*)out1 + (size_t)m * N + n) = o;
            } else if (mode == 3) {
                float4 bi = *(const float4*)(bias1 + n);
                f16x4 rr = *(const f16x4*)(resh + (size_t)m * 256 + n);
                float4 o = {v[0] + bi.x + (float)rr[0], v[1] + bi.y + (float)rr[1],
                            v[2] + bi.z + (float)rr[2], v[3] + bi.w + (float)rr[3]};
                *(float4*)((float*)out1 + (size_t)m * 256 + n) = o;
            } else {  // mode 4
                f16x4 o = {(f16)v[0], (f16)v[1], (f16)v[2], (f16)v[3]};
                *(f16x4*)((f16*)out1 + (size_t)m * 512 + 256 + n) = o;
            }
        }
    }
}

// ---------------------------------------------------------------- flash attention (S^T form)
// S^T = K Q^T; P^T feeds O^T = V^T P^T directly (B-frag of mfma_16x16x16).
// Fixed-shift softmax P = exp2(s-8). 128-q tile (tq=2, shared ka/va fragments).
// Grid x=bh (fast): all 16 q-tiles of one K/V panel on one XCD -> L2-served.
__global__ __launch_bounds__(256, 4) void k_flash(const f16* __restrict__ qkbuf,
                                                  const f16* __restrict__ vtbuf,
                                                  f16* __restrict__ mbuf) {
    const int z = blockIdx.z;
    const int bh = blockIdx.x;  // b*4+h (fast dim -> XCD-panel affinity)
    const int qt = blockIdx.y;  // 0..15
    const size_t HSZ = 2048 * 64;
    const size_t SSZ = 32 * HSZ;
    const f16* Q = qkbuf + (z ? SSZ : 0) + bh * HSZ;
    const f16* Kp = qkbuf + (z ? 0 : SSZ) + bh * HSZ;
    const f16* Vt = vtbuf + (z ? 0 : SSZ) + bh * HSZ;
    f16* Mo = mbuf + (size_t)z * (16384 * 256);

    __shared__ f16 Ks[2][4096];  // 64 rows x 64 cols, xor-swizzled 16B chunks
    __shared__ f16 Vs[2][4096];  // 64 d-rows x 64 kv-cols, same swizzle

    const int tid = threadIdx.x, lane = tid & 63, wave = tid >> 6;
    const int quad = lane >> 4, l16 = lane & 15;
    const int srow = lane >> 3;
    const int slc = (lane & 7) ^ (srow & 7);

    const int q0 = qt * 128 + wave * 32;
    f16x8 qf[2][2];
#pragma unroll
    for (int tq = 0; tq < 2; tq++)
#pragma unroll
        for (int kk = 0; kk < 2; kk++)
            qf[tq][kk] =
                *(const f16x8*)(Q + (size_t)(q0 + tq * 16 + l16) * 64 + kk * 32 + quad * 8);

    auto stage = [&](int buf, int kv0) {
#pragma unroll
        for (int i = 0; i < 2; i++) {
            const int widx = wave * 2 + i;
            const int row = widx * 8 + srow;
            load16(Kp + (size_t)(kv0 + row) * 64 + slc * 8, &Ks[buf][widx * 512]);
            load16(Vt + (size_t)row * 2048 + kv0 + slc * 8, &Vs[buf][widx * 512]);
        }
    };

    f32x4 oacc[4][2];
#pragma unroll
    for (int td = 0; td < 4; td++)
#pragma unroll
        for (int tq = 0; tq < 2; tq++) oacc[td][tq] = (f32x4){0.f, 0.f, 0.f, 0.f};
    float lrow[2] = {0.f, 0.f};

    stage(0, 0);
    __syncthreads();

    for (int t = 0; t < 32; t++) {
        const int cur = t & 1;
        if (t < 31) stage(cur ^ 1, (t + 1) * 64);
        const f16* Kc = Ks[cur];
        const f16* Vc = Vs[cur];

        f32x4 sacc[4][2];
#pragma unroll
        for (int tkv = 0; tkv < 4; tkv++)
#pragma unroll
            for (int tq = 0; tq < 2; tq++) sacc[tkv][tq] = (f32x4){0.f, 0.f, 0.f, 0.f};
#pragma unroll
        for (int kk = 0; kk < 2; kk++) {
#pragma unroll
            for (int tkv = 0; tkv < 4; tkv++) {
                const int r = tkv * 16 + l16;
                f16x8 ka = *(const f16x8*)(Kc + r * 64 + (((kk * 4 + quad) ^ (r & 7)) * 8));
#pragma unroll
                for (int tq = 0; tq < 2; tq++)
                    sacc[tkv][tq] = MFMA16(ka, qf[tq][kk], sacc[tkv][tq]);
            }
        }

        // fixed-shift softmax: P = exp2(s - 8), per-lane l partials only
        f16x4 pk[4][2];
#pragma unroll
        for (int tq = 0; tq < 2; tq++) {
            float rs = 0.f;
#pragma unroll
            for (int tkv = 0; tkv < 4; tkv++) {
                float p0 = __builtin_amdgcn_exp2f(sacc[tkv][tq][0] - 8.0f);
                float p1 = __builtin_amdgcn_exp2f(sacc[tkv][tq][1] - 8.0f);
                float p2 = __builtin_amdgcn_exp2f(sacc[tkv][tq][2] - 8.0f);
                float p3 = __builtin_amdgcn_exp2f(sacc[tkv][tq][3] - 8.0f);
                pk[tkv][tq] = (f16x4){(f16)p0, (f16)p1, (f16)p2, (f16)p3};
                rs += (p0 + p1) + (p2 + p3);
            }
            lrow[tq] += rs;
        }

#pragma unroll
        for (int tkv = 0; tkv < 4; tkv++) {
#pragma unroll
            for (int td = 0; td < 4; td++) {
                const int r = td * 16 + l16;
                f16x4 va = *(const f16x4*)(Vc + r * 64 +
                                           (((2 * tkv + (quad >> 1)) ^ (r & 7)) * 8) +
                                           (quad & 1) * 4);
#pragma unroll
                for (int tq = 0; tq < 2; tq++)
                    oacc[td][tq] = MFMA16K16(va, pk[tkv][tq], oacc[td][tq]);
            }
        }
        __syncthreads();
    }

    const int b = bh >> 2, h = bh & 3;
#pragma unroll
    for (int tq = 0; tq < 2; tq++) {
        float ls = lrow[tq];
        ls += __shfl_xor(ls, 16);
        ls += __shfl_xor(ls, 32);
        const float inv = 1.f / ls;
        const int q = q0 + tq * 16 + l16;
        const size_t base = ((size_t)(b * 2048 + q)) * 256 + h * 64;
#pragma unroll
        for (int td = 0; td < 4; td++) {
            f16x4 o = {(f16)(oacc[td][tq][0] * inv), (f16)(oacc[td][tq][1] * inv),
                       (f16)(oacc[td][tq][2] * inv), (f16)(oacc[td][tq][3] * inv)};
            *(f16x4*)(Mo + base + td * 16 + quad * 4) = o;
        }
    }
}

// ---------------------------------------------------------------- LN + GELU (wave per row)
__global__ __launch_bounds__(256) void k_ln_gelu(f16* __restrict__ h,
                                                 const float* __restrict__ g,
                                                 const float* __restrict__ bb) {
    const int tid = threadIdx.x, wave = tid >> 6, lane = tid & 63;
    const size_t row = (size_t)blockIdx.x * 4 + wave;
    f16* hr = h + row * 512 + lane * 8;
    f16x8 v = *(const f16x8*)hr;
    float x[8];
    float s = 0.f, sq = 0.f;
#pragma unroll
    for (int i = 0; i < 8; i++) {
        x[i] = (float)v[i];
        s += x[i];
        sq += x[i] * x[i];
    }
#pragma unroll
    for (int off = 1; off < 64; off <<= 1) {
        s += __shfl_xor(s, off);
        sq += __shfl_xor(sq, off);
    }
    const float mu = s * (1.f / 512.f);
    const float var = sq * (1.f / 512.f) - mu * mu;
    const float rstd = rsqrtf(var + 1e-5f);
    float4 g0 = *(const float4*)(g + lane * 8), g1 = *(const float4*)(g + lane * 8 + 4);
    float4 b0 = *(const float4*)(bb + lane * 8), b1 = *(const float4*)(bb + lane * 8 + 4);
    float gg[8] = {g0.x, g0.y, g0.z, g0.w, g1.x, g1.y, g1.z, g1.w};
    float bv[8] = {b0.x, b0.y, b0.z, b0.w, b1.x, b1.y, b1.z, b1.w};
#pragma unroll
    for (int i = 0; i < 8; i++) {
        float a = (x[i] - mu) * rstd * gg[i] + bv[i];
        a = 0.5f * a * (1.f + erff(a * 0.70710678118f));
        v[i] = (f16)a;
    }
    *(f16x8*)hr = v;
}

// ---------------------------------------------------------------- launch

extern "C" void kernel_launch(void* const* d_in, const int* in_sizes, int n_in, void* d_out,
                              int out_size, void* d_ws, size_t ws_size, hipStream_t stream) {
    const float* x0 = (const float*)d_in[0];
    const float* x1 = (const float*)d_in[1];
    const float* Wqk = (const float*)d_in[2];
    const float* bqk = (const float*)d_in[3];
    const float* Wv = (const float*)d_in[4];
    const float* bv = (const float*)d_in[5];
    const float* Wout = (const float*)d_in[6];
    const float* bout = (const float*)d_in[7];
    const float* W1 = (const float*)d_in[8];
    const float* b1 = (const float*)d_in[9];
    const float* lng = (const float*)d_in[10];
    const float* lnb = (const float*)d_in[11];
    const float* W2 = (const float*)d_in[12];
    const float* b2 = (const float*)d_in[13];
    float* out = (float*)d_out;

    char* ws = (char*)d_ws;
    f16* xh = (f16*)(ws);                 // 0..16M   (2,B,L,C) f16
    f16* qk = (f16*)(ws + 16777216);      // 16..32M  (2,B,H,L,D) f16 (scaled)
    f16* vt = (f16*)(ws + 33554432);      // 32..48M  (2,B,H,D,L) f16
    f16* mbuf = (f16*)(ws + 50331648);    // 48..64M  (2,B,L,C) f16 (flash out)
    f16* hbuf = qk;                       // 16..48M  (2,B,L,2C) f16 (qk+vt dead after flash)
    // transient (dead before proj writes qk): w1bt/woutf16 live in the qk region
    f16* w1bt = (f16*)(ws + 16777216);    // [512][256] f16
    f16* woutf16 = w1bt + 131072;         // [256][256] f16
    // persistent weights
    f16* wcat_t = (f16*)(ws + 67108864);  // [512][256]
    f16* w1t = wcat_t + 131072;           // [512][512] effective W1
    f16* w2t = w1t + 262144;              // [256][512]
    float* bias_eff = (float*)(w2t + 131072);  // [512] f32

    k_prep<<<11008, 256, 0, stream>>>(x0, x1, Wqk, Wv, W1, W2, Wout, b1, bout, xh, wcat_t, w1t,
                                      w1bt, w2t, woutf16, bias_eff);
    // WoW1b: w1t[:, 256:] = (Wout @ W1_bot)^T  (M=512, N=256, K=256)
    k_gemm<<<dim3(4, 1), 256, 0, stream>>>(w1bt, w1bt, 1 << 30, 256, woutf16, 256, 256, nullptr,
                                           nullptr, 4, w1t, nullptr, nullptr);
    // projections: [x0;x1] @ [Wqk|Wv] -> qk (scaled, head layout) + v^T
    k_gemm<<<dim3(256, 2), 256, 0, stream>>>(xh, xh, 1 << 30, 256, wcat_t, 256, 512, bqk, bv, 0,
                                             qk, vt, nullptr);
    // bidirectional flash attention -> mbuf
    k_flash<<<dim3(32, 16, 2), 256, 0, stream>>>(qk, vt, mbuf);
    // FFN1: [x | attn] @ Weff + bias_eff   (Wout folded in)
    k_gemm<<<dim3(256, 2), 256, 0, stream>>>(xh, mbuf, 256, 256, w1t, 512, 512, bias_eff,
                                             nullptr, 2, hbuf, nullptr, nullptr);
    k_ln_gelu<<<8192, 256, 0, stream>>>(hbuf, lng, lnb);
    // FFN2 + residual (f16 xh) -> fp32 out, single bn pass
    k_gemm<<<dim3(256, 1), 256, 0, stream>>>(hbuf, hbuf, 1 << 30, 512, w2t, 512, 256, b2,
                                             nullptr, 3, out, nullptr, xh);
}